// Round 4
// baseline (452.560 us; speedup 1.0000x reference)
//
#include <hip/hip_runtime.h>
#include <math.h>

// Problem shapes (fixed by reference setup_inputs):
constexpr int Bc = 8, Hc = 384, Wc = 1280, Cc = 8;

// ---------------- gather kernel ----------------
// One thread per OUTPUT pixel. Source (h,w) contributes to pixel (py,px)
// iff |w+fx-px| < 1 and |h+fy-py| < 1. With |f|<=2.5, contributing sources
// lie within +-3 -> 7x7 scan window. Sources with |f|>2.5 (P ~ 2.5% ->
// ~97K sources) are handled by the scatter kernel with global atomics,
// stream-ordered after this kernel's plain overwrite stores.
//
// Two-pass structure: pass 1 builds a 49-bit hit mask branchlessly (no
// loads, ~6 VALU/position); pass 2 iterates set bits only, so the
// load+FMA body runs at full lane density (each lane on its own hit).
constexpr int TH = 16, TW = 16;              // output tile per block (256 thr)
constexpr int WIN = 3;                        // window half-width
constexpr float FMAX = 2.5f;                  // flow split threshold (exact fp32 cmp in BOTH kernels)
constexpr int RH = TH + 2 * WIN;              // 22
constexpr int RW = TW + 2 * WIN;              // 22
constexpr int PSTR = RW + 1;                  // 23: padded LDS row stride (float2)
constexpr int TILES_X = Wc / TW;              // 80
constexpr int TILES_Y = Hc / TH;              // 24
constexpr int BLK = 256;

__global__ __launch_bounds__(BLK) void fwd_warp_gather(
    const float* __restrict__ U, const float* __restrict__ flo,
    float* __restrict__ out)
{
    // absolute splat coordinates (x,y) = (w+fx, h+fy) per source;
    // sentinel -1e9 for out-of-image or |f|>FMAX sources (never hits).
    __shared__ float2 sxy[RH * PSTR];         // 22*23*8 = 4048 B

    int tile = blockIdx.x;
    int b  = tile / (TILES_X * TILES_Y);
    int r  = tile % (TILES_X * TILES_Y);
    int Y0 = (r / TILES_X) * TH;
    int X0 = (r % TILES_X) * TW;
    int t  = threadIdx.x;

    const float2* flo2 = reinterpret_cast<const float2*>(flo);
    const float4* u4   = reinterpret_cast<const float4*>(U);

    // ---- stage splat coords (coalesced float2 reads) ----
    for (int i = t; i < RH * RW; i += BLK) {
        int sy = i / RW, sx = i - sy * RW;
        int h = Y0 - WIN + sy;
        int w = X0 - WIN + sx;
        float2 v = make_float2(-1e9f, -1e9f);
        if ((unsigned)h < (unsigned)Hc && (unsigned)w < (unsigned)Wc) {
            float2 f = flo2[(b * Hc + h) * Wc + w];
            if (fabsf(f.x) <= FMAX && fabsf(f.y) <= FMAX)
                v = make_float2((float)w + f.x, (float)h + f.y);
        }
        sxy[sy * PSTR + sx] = v;
    }
    __syncthreads();

    int lpy = t >> 4, lpx = t & 15;
    int py = Y0 + lpy, px = X0 + lpx;
    float pxf = (float)px, pyf = (float)py;
    int pixbase = (b * Hc + py) * Wc + px;

    // ---- pass 1: branchless 49-bit hit mask (packed dy*8+dx) ----
    unsigned long long mask = 0ull;
    #pragma unroll
    for (int dy = 0; dy < 2 * WIN + 1; ++dy) {
        int rb = (lpy + dy) * PSTR + lpx;
        #pragma unroll
        for (int dx = 0; dx < 2 * WIN + 1; ++dx) {
            float2 s = sxy[rb + dx];
            // strict < 1: boundary taps have exactly-zero weight (reference
            // skips nothing, but adding 0 is identity). Sentinels never pass.
            float m = fmaxf(fabsf(s.x - pxf), fabsf(s.y - pyf));
            unsigned long long hit = (m < 1.0f) ? 1ull : 0ull;
            mask |= hit << (dy * 8 + dx);
        }
    }

    // ---- pass 2: process only actual hits, full lane density ----
    float a0 = 0.f, a1 = 0.f, a2 = 0.f, a3 = 0.f;
    float a4 = 0.f, a5 = 0.f, a6 = 0.f, a7 = 0.f;
    while (mask) {
        int bit = __builtin_ctzll(mask);
        mask &= mask - 1;
        int dy = bit >> 3, dx = bit & 7;
        float2 s = sxy[(lpy + dy) * PSTR + lpx + dx];
        // (1-|x-px|)(1-|y-py|) == the reference bilinear weight for this tap
        float wgt = (1.0f - fabsf(s.x - pxf)) * (1.0f - fabsf(s.y - pyf));
        int sidx = pixbase + (dy - WIN) * Wc + (dx - WIN);
        float4 ua = u4[(size_t)sidx * 2];
        float4 ub = u4[(size_t)sidx * 2 + 1];
        a0 += ua.x * wgt; a1 += ua.y * wgt;
        a2 += ua.z * wgt; a3 += ua.w * wgt;
        a4 += ub.x * wgt; a5 += ub.y * wgt;
        a6 += ub.z * wgt; a7 += ub.w * wgt;
    }

    // plain coalesced stores (no atomics): full overwrite of my pixel
    float4 o0 = {a0, a1, a2, a3};
    float4 o1 = {a4, a5, a6, a7};
    reinterpret_cast<float4*>(out)[(size_t)pixbase * 2]     = o0;
    reinterpret_cast<float4*>(out)[(size_t)pixbase * 2 + 1] = o1;
}

// ---------------- outlier scatter kernel ----------------
// Handles sources with |f|>FMAX exactly like the reference (clamp +
// zero-weight logic), adding into 'out' with global atomics AFTER the gather
// kernel has fully written it (same stream -> ordered). ~2.5% of sources.
__global__ __launch_bounds__(BLK) void fwd_warp_outlier(
    const float* __restrict__ U, const float* __restrict__ flo,
    float* __restrict__ out)
{
    int tid = blockIdx.x * BLK + threadIdx.x;
    int total = Bc * Hc * Wc;
    if (tid >= total) return;
    float2 f = reinterpret_cast<const float2*>(flo)[tid];
    if (fabsf(f.x) <= FMAX && fabsf(f.y) <= FMAX) return;   // exact complement of gather predicate

    int w = tid % Wc;
    int h = (tid / Wc) % Hc;
    float x = (float)w + f.x;
    float y = (float)h + f.y;
    float x0f = floorf(x), y0f = floorf(y);
    int x0 = (int)x0f, y0 = (int)y0f;
    float wx[2] = { (x0f + 1.0f) - x, x - x0f };
    float wy[2] = { (y0f + 1.0f) - y, y - y0f };

    const float4* u4 = reinterpret_cast<const float4*>(U);
    float4 ua = u4[(size_t)tid * 2];
    float4 ub = u4[(size_t)tid * 2 + 1];
    int bbase = tid - (h * Wc + w);           // b*Hc*Wc

    #pragma unroll
    for (int j = 0; j < 2; ++j) {
        #pragma unroll
        for (int k = 0; k < 2; ++k) {
            int ty = y0 + j, tx = x0 + k;
            if ((unsigned)ty < (unsigned)Hc && (unsigned)tx < (unsigned)Wc) {
                float wgt = wx[k] * wy[j];
                if (wgt != 0.0f) {
                    float* p = out + ((size_t)(bbase + ty * Wc + tx)) * 8;
                    atomicAdd(p + 0, ua.x * wgt);
                    atomicAdd(p + 1, ua.y * wgt);
                    atomicAdd(p + 2, ua.z * wgt);
                    atomicAdd(p + 3, ua.w * wgt);
                    atomicAdd(p + 4, ub.x * wgt);
                    atomicAdd(p + 5, ub.y * wgt);
                    atomicAdd(p + 6, ub.z * wgt);
                    atomicAdd(p + 7, ub.w * wgt);
                }
            }
        }
    }
}

extern "C" void kernel_launch(void* const* d_in, const int* in_sizes, int n_in,
                              void* d_out, int out_size, void* d_ws, size_t ws_size,
                              hipStream_t stream)
{
    const float* U   = (const float*)d_in[0];
    const float* flo = (const float*)d_in[1];
    float* out = (float*)d_out;

    int grid_g = Bc * TILES_X * TILES_Y;            // 15360 tiles
    fwd_warp_gather<<<grid_g, BLK, 0, stream>>>(U, flo, out);

    int grid_o = (Bc * Hc * Wc + BLK - 1) / BLK;    // 15360 blocks
    fwd_warp_outlier<<<grid_o, BLK, 0, stream>>>(U, flo, out);
}

// Round 5
// 437.198 us; speedup vs baseline: 1.0351x; 1.0351x over previous
//
#include <hip/hip_runtime.h>
#include <math.h>

// Problem shapes (fixed by reference setup_inputs):
constexpr int Bc = 8, Hc = 384, Wc = 1280, Cc = 8;

// ---------------- gather kernel ----------------
// One thread per OUTPUT pixel. Source (h,w) contributes to pixel (py,px)
// iff |w+fx-px| < 1 and |h+fy-py| < 1. With |f|<=WIN, contributing sources
// lie within the (2*WIN+1)^2 window EXACTLY: a source at integer offset
// d >= WIN+1 with |f| <= WIN has |d+f| >= 1 -> fails the strict <1 test.
// So FMAX = WIN = 3 drops no taps. Sources with |f|>3 (~21K of 3.9M) are
// appended to a compact list during staging (each pixel is interior to
// exactly one tile -> appended exactly once) and processed by a tiny
// list-driven scatter kernel with global atomics, stream-ordered after
// this kernel's plain overwrite stores.
constexpr int TH = 16, TW = 16;              // output tile per block (256 thr)
constexpr int WIN = 3;                        // window half-width
constexpr float FMAX = 3.0f;                  // = WIN (exactness bound)
constexpr int RH = TH + 2 * WIN;              // 22
constexpr int RW = TW + 2 * WIN;              // 22
constexpr int PSTR = RW + 1;                  // 23: padded LDS row stride
constexpr int TILES_X = Wc / TW;              // 80
constexpr int TILES_Y = Hc / TH;              // 24
constexpr int BLK = 256;
constexpr unsigned LIST_CAP = 262144;         // 1 MB of u32 entries
constexpr size_t WS_NEED = 16 + (size_t)LIST_CAP * 4;

__global__ __launch_bounds__(BLK) void fwd_warp_gather(
    const float* __restrict__ U, const float* __restrict__ flo,
    float* __restrict__ out, unsigned* __restrict__ ws, int do_append)
{
    // splat coords (x,y)=(w+fx,h+fy) per source; sentinel -1e9 never hits.
    __shared__ float2 sxy[RH * PSTR];         // 4048 B
    __shared__ float4 sU[RH * PSTR * 2];      // 16192 B  (U staged: pass-2 hits read LDS, not global)

    int tile = blockIdx.x;
    int b  = tile / (TILES_X * TILES_Y);
    int r  = tile % (TILES_X * TILES_Y);
    int Y0 = (r / TILES_X) * TH;
    int X0 = (r % TILES_X) * TW;
    int t  = threadIdx.x;

    const float2* flo2 = reinterpret_cast<const float2*>(flo);
    const float4* u4   = reinterpret_cast<const float4*>(U);

    // ---- stage splat coords + U (coalesced), append interior outliers ----
    for (int i = t; i < RH * RW; i += BLK) {
        int sy = i / RW, sx = i - sy * RW;
        int h = Y0 - WIN + sy;
        int w = X0 - WIN + sx;
        bool inimg = ((unsigned)h < (unsigned)Hc) & ((unsigned)w < (unsigned)Wc);
        int hc = min(max(h, 0), Hc - 1);
        int wc = min(max(w, 0), Wc - 1);
        int sidx = (b * Hc + hc) * Wc + wc;
        float2 f  = flo2[sidx];
        float4 ua = u4[(size_t)sidx * 2];
        float4 ub = u4[(size_t)sidx * 2 + 1];
        bool inl = (fabsf(f.x) <= FMAX) && (fabsf(f.y) <= FMAX);
        float2 v = (inimg && inl) ? make_float2((float)w + f.x, (float)h + f.y)
                                  : make_float2(-1e9f, -1e9f);
        int st = sy * PSTR + sx;
        sxy[st]        = v;
        sU[st * 2]     = ua;
        sU[st * 2 + 1] = ub;
        // exact complement predicate, interior ownership -> appended once
        if (do_append && inimg && !inl &&
            sy >= WIN && sy < WIN + TH && sx >= WIN && sx < WIN + TW) {
            unsigned pos = atomicAdd(ws, 1u);
            if (pos < LIST_CAP) ws[4 + pos] = (unsigned)sidx;
        }
    }
    __syncthreads();

    int lpy = t >> 4, lpx = t & 15;
    int py = Y0 + lpy, px = X0 + lpx;
    float pxf = (float)px, pyf = (float)py;
    int pixbase = (b * Hc + py) * Wc + px;

    // ---- pass 1: branchless 49-bit hit mask (packed dy*8+dx) ----
    unsigned long long mask = 0ull;
    #pragma unroll
    for (int dy = 0; dy < 2 * WIN + 1; ++dy) {
        int rb = (lpy + dy) * PSTR + lpx;
        #pragma unroll
        for (int dx = 0; dx < 2 * WIN + 1; ++dx) {
            float2 s = sxy[rb + dx];
            float m = fmaxf(fabsf(s.x - pxf), fabsf(s.y - pyf));
            unsigned long long hit = (m < 1.0f) ? 1ull : 0ull;
            mask |= hit << (dy * 8 + dx);
        }
    }

    // ---- pass 2: process only actual hits, full lane density, LDS-fed ----
    float a0 = 0.f, a1 = 0.f, a2 = 0.f, a3 = 0.f;
    float a4 = 0.f, a5 = 0.f, a6 = 0.f, a7 = 0.f;
    while (mask) {
        int bit = __builtin_ctzll(mask);
        mask &= mask - 1;
        int dy = bit >> 3, dx = bit & 7;
        int st = (lpy + dy) * PSTR + lpx + dx;
        float2 s = sxy[st];
        // (1-|x-px|)(1-|y-py|) == reference bilinear weight for this tap
        float wgt = (1.0f - fabsf(s.x - pxf)) * (1.0f - fabsf(s.y - pyf));
        float4 ua = sU[st * 2];
        float4 ub = sU[st * 2 + 1];
        a0 += ua.x * wgt; a1 += ua.y * wgt;
        a2 += ua.z * wgt; a3 += ua.w * wgt;
        a4 += ub.x * wgt; a5 += ub.y * wgt;
        a6 += ub.z * wgt; a7 += ub.w * wgt;
    }

    // plain coalesced stores (no atomics): full overwrite of my pixel
    float4 o0 = {a0, a1, a2, a3};
    float4 o1 = {a4, a5, a6, a7};
    reinterpret_cast<float4*>(out)[(size_t)pixbase * 2]     = o0;
    reinterpret_cast<float4*>(out)[(size_t)pixbase * 2 + 1] = o1;
}

// ---------------- list-driven outlier scatter ----------------
// Processes ONLY the compacted outlier list (no full flo scan). Reference
// semantics (clamp + zero-weight skip), global atomics, stream-ordered
// after the gather's plain stores.
__global__ __launch_bounds__(BLK) void fwd_warp_outlier_list(
    const float* __restrict__ U, const float* __restrict__ flo,
    float* __restrict__ out, const unsigned* __restrict__ ws)
{
    unsigned n = min(ws[0], LIST_CAP);
    for (unsigned i = blockIdx.x * BLK + threadIdx.x; i < n;
         i += gridDim.x * BLK) {
        int sidx = (int)ws[4 + i];
        int w = sidx % Wc;
        int h = (sidx / Wc) % Hc;
        float2 f = reinterpret_cast<const float2*>(flo)[sidx];

        float x = (float)w + f.x;
        float y = (float)h + f.y;
        float x0f = floorf(x), y0f = floorf(y);
        int x0 = (int)x0f, y0 = (int)y0f;
        float wx[2] = { (x0f + 1.0f) - x, x - x0f };
        float wy[2] = { (y0f + 1.0f) - y, y - y0f };

        const float4* u4 = reinterpret_cast<const float4*>(U);
        float4 ua = u4[(size_t)sidx * 2];
        float4 ub = u4[(size_t)sidx * 2 + 1];
        int bbase = sidx - (h * Wc + w);      // b*Hc*Wc

        #pragma unroll
        for (int j = 0; j < 2; ++j) {
            #pragma unroll
            for (int k = 0; k < 2; ++k) {
                int ty = y0 + j, tx = x0 + k;
                if ((unsigned)ty < (unsigned)Hc && (unsigned)tx < (unsigned)Wc) {
                    float wgt = wx[k] * wy[j];
                    if (wgt != 0.0f) {
                        float* p = out + ((size_t)(bbase + ty * Wc + tx)) * 8;
                        atomicAdd(p + 0, ua.x * wgt);
                        atomicAdd(p + 1, ua.y * wgt);
                        atomicAdd(p + 2, ua.z * wgt);
                        atomicAdd(p + 3, ua.w * wgt);
                        atomicAdd(p + 4, ub.x * wgt);
                        atomicAdd(p + 5, ub.y * wgt);
                        atomicAdd(p + 6, ub.z * wgt);
                        atomicAdd(p + 7, ub.w * wgt);
                    }
                }
            }
        }
    }
}

// ---------------- fallback full-scan outlier (only if ws too small) ----------------
__global__ __launch_bounds__(BLK) void fwd_warp_outlier_scan(
    const float* __restrict__ U, const float* __restrict__ flo,
    float* __restrict__ out)
{
    int tid = blockIdx.x * BLK + threadIdx.x;
    int total = Bc * Hc * Wc;
    if (tid >= total) return;
    float2 f = reinterpret_cast<const float2*>(flo)[tid];
    if (fabsf(f.x) <= FMAX && fabsf(f.y) <= FMAX) return;

    int w = tid % Wc;
    int h = (tid / Wc) % Hc;
    float x = (float)w + f.x;
    float y = (float)h + f.y;
    float x0f = floorf(x), y0f = floorf(y);
    int x0 = (int)x0f, y0 = (int)y0f;
    float wx[2] = { (x0f + 1.0f) - x, x - x0f };
    float wy[2] = { (y0f + 1.0f) - y, y - y0f };

    const float4* u4 = reinterpret_cast<const float4*>(U);
    float4 ua = u4[(size_t)tid * 2];
    float4 ub = u4[(size_t)tid * 2 + 1];
    int bbase = tid - (h * Wc + w);

    #pragma unroll
    for (int j = 0; j < 2; ++j) {
        #pragma unroll
        for (int k = 0; k < 2; ++k) {
            int ty = y0 + j, tx = x0 + k;
            if ((unsigned)ty < (unsigned)Hc && (unsigned)tx < (unsigned)Wc) {
                float wgt = wx[k] * wy[j];
                if (wgt != 0.0f) {
                    float* p = out + ((size_t)(bbase + ty * Wc + tx)) * 8;
                    atomicAdd(p + 0, ua.x * wgt);
                    atomicAdd(p + 1, ua.y * wgt);
                    atomicAdd(p + 2, ua.z * wgt);
                    atomicAdd(p + 3, ua.w * wgt);
                    atomicAdd(p + 4, ub.x * wgt);
                    atomicAdd(p + 5, ub.y * wgt);
                    atomicAdd(p + 6, ub.z * wgt);
                    atomicAdd(p + 7, ub.w * wgt);
                }
            }
        }
    }
}

extern "C" void kernel_launch(void* const* d_in, const int* in_sizes, int n_in,
                              void* d_out, int out_size, void* d_ws, size_t ws_size,
                              hipStream_t stream)
{
    const float* U   = (const float*)d_in[0];
    const float* flo = (const float*)d_in[1];
    float* out = (float*)d_out;
    unsigned* ws = (unsigned*)d_ws;

    bool use_list = (ws != nullptr) && (ws_size >= WS_NEED);
    int grid_g = Bc * TILES_X * TILES_Y;            // 15360 tiles

    if (use_list) {
        hipMemsetAsync(d_ws, 0, 16, stream);        // zero the append counter
        fwd_warp_gather<<<grid_g, BLK, 0, stream>>>(U, flo, out, ws, 1);
        fwd_warp_outlier_list<<<256, BLK, 0, stream>>>(U, flo, out, ws);
    } else {
        fwd_warp_gather<<<grid_g, BLK, 0, stream>>>(U, flo, out, ws, 0);
        int grid_o = (Bc * Hc * Wc + BLK - 1) / BLK;
        fwd_warp_outlier_scan<<<grid_o, BLK, 0, stream>>>(U, flo, out);
    }
}